// Round 14
// baseline (901.374 us; speedup 1.0000x reference)
//
#include <hip/hip_runtime.h>
#include <hip/hip_bf16.h>

constexpr int N_NODES  = 50000;
constexpr int N_EDGES  = 400000;
constexpr int EDGE_DIM = 144;
constexpr int HEADS    = 16;
constexpr int HEAD_DIM = 32;
constexpr int OUTD     = 512;   // HEADS*HEAD_DIM
constexpr int HID      = 64;
constexpr int NES      = 16;
constexpr int NNS      = 64;
constexpr int SCAN_B   = 512;
constexpr int NSB      = (N_NODES + SCAN_B - 1) / SCAN_B;   // 98
constexpr int NPB_A    = 64;    // nodes per block, papply
#define ISQRTD 0.17677669529663687f

__device__ __forceinline__ float silu_f(float x) {
    return x / (1.0f + __expf(-x));
}

__device__ __forceinline__ unsigned fenc(float f) {
    unsigned u = __float_as_uint(f);
    return (u & 0x80000000u) ? ~u : (u | 0x80000000u);
}
__device__ __forceinline__ float fdec(unsigned m) {
    unsigned u = (m & 0x80000000u) ? (m ^ 0x80000000u) : ~m;
    return __uint_as_float(u);
}

__device__ __forceinline__ int headOf(int col) {
    return (col < 16) ? col : ((col < 64) ? (col - 16) / 3 : (col - 64) / 5);
}

__device__ __forceinline__ void storeQ(float* p, float v) { *p = v; }
__device__ __forceinline__ void storeQ(__hip_bfloat16* p, float v) { *p = __float2bfloat16(v); }
__device__ __forceinline__ float loadQ(const float* p) { return *p; }
__device__ __forceinline__ float loadQ(const __hip_bfloat16* p) { return __bfloat162float(*p); }

// -------- prep: transpose k_w1 (16x64 -> 64x16) and k_w2 (64x64) -------------
__global__ __launch_bounds__(256) void prep_kernel(
    const float* __restrict__ w1, const float* __restrict__ w2,
    float* __restrict__ w1T, float* __restrict__ w2T) {
    int t = blockIdx.x * 256 + threadIdx.x;
    if (t < NES * HID) {
        int i = t / HID, j = t % HID;
        w1T[j * NES + i] = w1[t];
    }
    if (t < HID * HID) {
        int i = t / HID, j = t % HID;
        w2T[j * HID + i] = w2[t];
    }
}

// -------- mbuild: M[hg][i][j][hl], C0[hg][i][hl], Mb[h][j], c1[h] ------------
__global__ __launch_bounds__(256) void mbuild_kernel(
    const float* __restrict__ qw3, const float* __restrict__ qb3,
    const float* __restrict__ kw3, const float* __restrict__ kb3,
    float* __restrict__ M, float* __restrict__ C0,
    float* __restrict__ Mb, float* __restrict__ c1) {
    const int b = blockIdx.x, t = threadIdx.x;
    if (b < 256) {                     // M: 65536 entries
        const int o  = b * 256 + t;
        const int hl = o & 3, j = (o >> 2) & 63, i = (o >> 8) & 63, hg = o >> 14;
        const int h  = hg * 4 + hl;
        const float* ka = kw3 + (size_t)i * OUTD + h * HEAD_DIM;
        const float* qa = qw3 + (size_t)j * OUTD + h * HEAD_DIM;
        float s = 0.f;
        #pragma unroll
        for (int d = 0; d < HEAD_DIM; ++d) s += ka[d] * qa[d];
        M[o] = s;
    } else if (b < 260) {              // C0: 1024 entries, layout [hg][i][hl]
        const int o  = (b - 256) * 256 + t;
        const int hl = o & 3, i = (o >> 2) & 63, hg = o >> 8;
        const int h  = hg * 4 + hl;
        float s = 0.f;
        #pragma unroll
        for (int d = 0; d < HEAD_DIM; ++d)
            s += kw3[(size_t)i * OUTD + h * HEAD_DIM + d] * qb3[h * HEAD_DIM + d];
        C0[o] = s;
    } else if (b < 264) {              // Mb: [h][j]
        const int o = (b - 260) * 256 + t;
        const int h = o >> 6, j = o & 63;
        float s = 0.f;
        #pragma unroll
        for (int d = 0; d < HEAD_DIM; ++d)
            s += kb3[h * HEAD_DIM + d] * qw3[(size_t)j * OUTD + h * HEAD_DIM + d];
        Mb[o] = s;
    } else {                           // c1: 16
        if (t < HEADS) {
            float s = 0.f;
            #pragma unroll
            for (int d = 0; d < HEAD_DIM; ++d)
                s += kb3[t * HEAD_DIM + d] * qb3[t * HEAD_DIM + d];
            c1[t] = s;
        }
    }
}

// -------- h2q: Q-MLP layers 1-2 per node + Sn = h2.Mb + c1 -------------------
__global__ __launch_bounds__(256) void h2q_kernel(
    const float* __restrict__ node_attrs,
    const float* __restrict__ w1, const float* __restrict__ b1,
    const float* __restrict__ w2, const float* __restrict__ b2,
    const float* __restrict__ Mb, const float* __restrict__ c1,
    float* __restrict__ h2buf, float* __restrict__ Sn) {
    __shared__ float xs[4][NNS];
    __shared__ float h1s[4][HID];
    __shared__ float h2s[4][HID];
    __shared__ float Mbs[HEADS][65];
    __shared__ float c1s[HEADS];
    const int t = threadIdx.x, wid = t >> 6, lane = t & 63;
    for (int o = t; o < HEADS * HID; o += 256) Mbs[o >> 6][o & 63] = Mb[o];
    if (t < HEADS) c1s[t] = c1[t];

    const int n = blockIdx.x * 4 + wid;
    const bool act = n < N_NODES;
    xs[wid][lane] = act ? node_attrs[(size_t)n * NNS + lane] : 0.0f;
    __syncthreads();

    float a = b1[lane];
    #pragma unroll
    for (int i = 0; i < NNS; ++i) a += xs[wid][i] * w1[i * HID + lane];
    h1s[wid][lane] = silu_f(a);
    __syncthreads();

    float a2 = b2[lane];
    #pragma unroll
    for (int i = 0; i < HID; ++i) a2 += h1s[wid][i] * w2[i * HID + lane];
    const float h2v = silu_f(a2);
    h2s[wid][lane] = h2v;
    if (act) h2buf[(size_t)n * HID + lane] = h2v;
    __syncthreads();

    const int h = lane & 15, q = lane >> 4;
    float s = 0.f;
    #pragma unroll
    for (int jj = 0; jj < 16; ++jj) s += h2s[wid][q * 16 + jj] * Mbs[h][q * 16 + jj];
    s += __shfl_xor(s, 16);
    s += __shfl_xor(s, 32);
    if (act && lane < HEADS) Sn[(size_t)n * HEADS + lane] = s + c1s[lane];
}

// -------- papply: P[n][hg][j][hl] = h2.Mreg + C0 (persistent M regs) ---------
__global__ __launch_bounds__(256) void papply_kernel(
    const float* __restrict__ h2buf, const float* __restrict__ M,
    const float* __restrict__ C0, float* __restrict__ Pn) {
    const int t  = threadIdx.x;
    const int hg = blockIdx.y;

    float Mreg[HID];
    const float* msrc = M + (size_t)hg * 16384 + (t >> 2) * 256 + (t & 3);
    #pragma unroll
    for (int j = 0; j < HID; ++j) Mreg[j] = msrc[j * 4];
    const float c0 = C0[hg * 256 + t];

    __shared__ float h2s[4][HID];
    const int n0 = blockIdx.x * NPB_A;
    #pragma unroll 1
    for (int s4 = 0; s4 < NPB_A / 4; ++s4) {
        const int nb = n0 + s4 * 4;
        const int nl = nb + (t >> 6);
        const float v = (nl < N_NODES) ? h2buf[(size_t)nl * HID + (t & 63)] : 0.f;
        __syncthreads();
        h2s[t >> 6][t & 63] = v;
        __syncthreads();
        #pragma unroll 1
        for (int mm = 0; mm < 4; ++mm) {
            const int n = nb + mm;
            if (n >= N_NODES) break;
            float acc0 = c0, acc1 = 0.f;
            #pragma unroll
            for (int j = 0; j < HID; j += 2) {
                acc0 += h2s[mm][j]     * Mreg[j];
                acc1 += h2s[mm][j + 1] * Mreg[j + 1];
            }
            Pn[(size_t)n * 1024 + hg * 256 + t] = acc0 + acc1;
        }
    }
}

// -------- CSR build ----------------------------------------------------------
__global__ __launch_bounds__(256) void zero_counts_kernel(int* __restrict__ counts) {
    int t = blockIdx.x * 256 + threadIdx.x;
    if (t < N_NODES) counts[t] = 0;
}
__global__ __launch_bounds__(256) void hist_kernel(const int* __restrict__ center,
                                                   int* __restrict__ counts) {
    int e = blockIdx.x * 256 + threadIdx.x;
    if (e < N_EDGES) atomicAdd(&counts[center[e]], 1);
}
__global__ __launch_bounds__(SCAN_B) void scan1_kernel(
    const int* __restrict__ counts, int* __restrict__ incl, int* __restrict__ blockSums) {
    __shared__ int sm[SCAN_B];
    const int gid = blockIdx.x * SCAN_B + threadIdx.x;
    sm[threadIdx.x] = (gid < N_NODES) ? counts[gid] : 0;
    __syncthreads();
    #pragma unroll 1
    for (int off = 1; off < SCAN_B; off <<= 1) {
        int t = (threadIdx.x >= off) ? sm[threadIdx.x - off] : 0;
        __syncthreads();
        sm[threadIdx.x] += t;
        __syncthreads();
    }
    if (gid < N_NODES) incl[gid] = sm[threadIdx.x];
    if (threadIdx.x == SCAN_B - 1) blockSums[blockIdx.x] = sm[threadIdx.x];
}
__global__ void scan2_kernel(int* __restrict__ blockSums) {
    if (threadIdx.x == 0 && blockIdx.x == 0) {
        int run = 0;
        for (int i = 0; i < NSB; ++i) { int t = blockSums[i]; blockSums[i] = run; run += t; }
    }
}
__global__ __launch_bounds__(SCAN_B) void scan3_kernel(
    const int* __restrict__ counts, const int* __restrict__ incl,
    const int* __restrict__ blockSums, int* __restrict__ rowStart,
    int* __restrict__ cursor) {
    const int gid = blockIdx.x * SCAN_B + threadIdx.x;
    if (gid < N_NODES) {
        const int excl = incl[gid] - counts[gid] + blockSums[blockIdx.x];
        rowStart[gid] = excl;
        cursor[gid]   = excl;
    }
    if (gid == 0) rowStart[N_NODES] = N_EDGES;
}
__global__ __launch_bounds__(256) void fill_kernel(const int* __restrict__ center,
                                                   int* __restrict__ cursor,
                                                   int* __restrict__ edgeList,
                                                   int* __restrict__ nodeOf) {
    int e = blockIdx.x * 256 + threadIdx.x;
    if (e < N_EDGES) {
        const int c = center[e];
        int pos = atomicAdd(&cursor[c], 1);
        edgeList[pos] = e;
        nodeOf[pos]   = c;
    }
}

// -------- W-pass v8: 2 threads/edge, h1 split across lane pair ---------------
// Thread half=t&1 owns h1[half*32..+31] (registers) and heads [half*8..+8).
__global__ __launch_bounds__(256) void wpass8_kernel(
    const int* __restrict__ edgeList, const int* __restrict__ nodeOf,
    const float* __restrict__ edge_feat,
    const float* __restrict__ w1T, const float* __restrict__ b1,
    const float* __restrict__ w2T, const float* __restrict__ b2,
    const float* __restrict__ Pn, const float* __restrict__ Sn,
    float* __restrict__ Wbuf) {
    const int t    = threadIdx.x;
    const int half = t & 1;
    const int el   = t >> 1;                 // local edge 0..127
    const int slot = blockIdx.x * 128 + el;
    const bool act = slot < N_EDGES;

    int e = 0, c = 0;
    if (act) { e = edgeList[slot]; c = nodeOf[slot]; }

    float x[NES];
    {
        const float4* ef4 = reinterpret_cast<const float4*>(edge_feat + (size_t)e * EDGE_DIM);
        #pragma unroll
        for (int i = 0; i < NES / 4; ++i) {
            float4 v = act ? ef4[i] : make_float4(0.f, 0.f, 0.f, 0.f);
            x[4*i+0] = v.x; x[4*i+1] = v.y; x[4*i+2] = v.z; x[4*i+3] = v.w;
        }
    }

    // layer 1: my 32 h1 values (j = half*32 + jj)
    float h1r[32];
    #pragma unroll
    for (int jj = 0; jj < 32; ++jj) {
        const int j = half * 32 + jj;
        const float* wr = w1T + j * NES;
        float a0 = 0.f, a1 = 0.f, a2 = 0.f, a3 = 0.f;
        #pragma unroll
        for (int i = 0; i < NES; i += 4) {
            a0 += x[i + 0] * wr[i + 0];
            a1 += x[i + 1] * wr[i + 1];
            a2 += x[i + 2] * wr[i + 2];
            a3 += x[i + 3] * wr[i + 3];
        }
        h1r[jj] = silu_f(b1[j] + ((a0 + a1) + (a2 + a3)));
    }

    // wacc for my 8 heads (head groups 2*half, 2*half+1), seeded with Sn
    float wacc[8];
    {
        const float4* s4 = (const float4*)(Sn + (size_t)c * HEADS + half * 8);
        const float4 v0 = s4[0], v1 = s4[1];
        wacc[0] = v0.x; wacc[1] = v0.y; wacc[2] = v0.z; wacc[3] = v0.w;
        wacc[4] = v1.x; wacc[5] = v1.y; wacc[6] = v1.z; wacc[7] = v1.w;
    }

    // layer 2 + P-dot: partial dot over my 32 i's, pair-reduce, silu, 8-head FMA
    const float* ph = Pn + (size_t)c * 1024 + (half * 2) * 256;   // my 2 head-groups
    #pragma unroll 4
    for (int j = 0; j < HID; ++j) {
        const float* wr = w2T + j * HID + half * 32;
        float a0 = 0.f, a1 = 0.f, a2 = 0.f, a3 = 0.f;
        #pragma unroll
        for (int i = 0; i < 32; i += 4) {
            a0 += h1r[i + 0] * wr[i + 0];
            a1 += h1r[i + 1] * wr[i + 1];
            a2 += h1r[i + 2] * wr[i + 2];
            a3 += h1r[i + 3] * wr[i + 3];
        }
        float part = (a0 + a1) + (a2 + a3);
        part += __shfl_xor(part, 1);                 // pair-complete dot
        const float h2 = silu_f(b2[j] + part);
        const float4 p0 = *(const float4*)(ph + j * 4);          // hg = 2*half
        const float4 p1 = *(const float4*)(ph + 256 + j * 4);    // hg = 2*half+1
        wacc[0] += h2 * p0.x; wacc[1] += h2 * p0.y;
        wacc[2] += h2 * p0.z; wacc[3] += h2 * p0.w;
        wacc[4] += h2 * p1.x; wacc[5] += h2 * p1.y;
        wacc[6] += h2 * p1.z; wacc[7] += h2 * p1.w;
    }

    if (act) {
        float4* wrow = (float4*)(Wbuf + (size_t)slot * HEADS + half * 8);
        wrow[0] = make_float4(wacc[0] * ISQRTD, wacc[1] * ISQRTD,
                              wacc[2] * ISQRTD, wacc[3] * ISQRTD);
        wrow[1] = make_float4(wacc[4] * ISQRTD, wacc[5] * ISQRTD,
                              wacc[6] * ISQRTD, wacc[7] * ISQRTD);
    }
}

// -------- node gather v4: softmax + weighted sum, 4 rows in flight -----------
__global__ __launch_bounds__(256) void gather4_kernel(
    const int* __restrict__ rowStart, const int* __restrict__ edgeList,
    const float* __restrict__ edge_feat, const float* __restrict__ Wbuf,
    float* __restrict__ out) {
    const int wid  = threadIdx.x >> 6;
    const int lane = threadIdx.x & 63;
    const int n = blockIdx.x * 4 + wid;
    if (n >= N_NODES) return;
    const int rs = rowStart[n];
    const int d  = rowStart[n + 1] - rs;

    const int c0 = lane, c1 = lane + 64, c2 = lane + 128;
    const int h0 = headOf(c0);
    const int h1 = headOf(c1);
    const int h2 = (c2 < EDGE_DIM) ? headOf(c2) : 0;
    const bool has2 = (c2 < EDGE_DIM);

    float acc0 = 0.f, acc1 = 0.f, acc2 = 0.f;
    if (d > 0) {
        const int hh  = lane & 15;
        const int sub = lane >> 4;
        float m = -3.0e38f;
        for (int i = sub; i < d; i += 4)
            m = fmaxf(m, Wbuf[(size_t)(rs + i) * HEADS + hh]);
        m = fmaxf(m, __shfl_xor(m, 16));
        m = fmaxf(m, __shfl_xor(m, 32));
        float s = 0.f;
        for (int i = sub; i < d; i += 4)
            s += __expf(Wbuf[(size_t)(rs + i) * HEADS + hh] - m);
        s += __shfl_xor(s, 16);
        s += __shfl_xor(s, 32);
        const float rden = 1.0f / s;

        int i = 0;
        for (; i + 4 <= d; i += 4) {
            const int eA = edgeList[rs + i + 0];
            const int eB = edgeList[rs + i + 1];
            const int eC = edgeList[rs + i + 2];
            const int eD = edgeList[rs + i + 3];
            const float wA = Wbuf[(size_t)(rs + i + 0) * HEADS + hh];
            const float wB = Wbuf[(size_t)(rs + i + 1) * HEADS + hh];
            const float wC = Wbuf[(size_t)(rs + i + 2) * HEADS + hh];
            const float wD = Wbuf[(size_t)(rs + i + 3) * HEADS + hh];
            const float* frA = edge_feat + (size_t)eA * EDGE_DIM;
            const float* frB = edge_feat + (size_t)eB * EDGE_DIM;
            const float* frC = edge_feat + (size_t)eC * EDGE_DIM;
            const float* frD = edge_feat + (size_t)eD * EDGE_DIM;
            const float fA0 = frA[c0], fB0 = frB[c0], fC0 = frC[c0], fD0 = frD[c0];
            const float fA1 = frA[c1], fB1 = frB[c1], fC1 = frC[c1], fD1 = frD[c1];
            const float fA2 = has2 ? frA[c2] : 0.f;
            const float fB2 = has2 ? frB[c2] : 0.f;
            const float fC2 = has2 ? frC[c2] : 0.f;
            const float fD2 = has2 ? frD[c2] : 0.f;

            const float aLA = __expf(wA - m) * rden;
            const float aLB = __expf(wB - m) * rden;
            const float aLC = __expf(wC - m) * rden;
            const float aLD = __expf(wD - m) * rden;
            const float aA0 = __shfl(aLA, h0), aB0 = __shfl(aLB, h0);
            const float aC0 = __shfl(aLC, h0), aD0 = __shfl(aLD, h0);
            const float aA1 = __shfl(aLA, h1), aB1 = __shfl(aLB, h1);
            const float aC1 = __shfl(aLC, h1), aD1 = __shfl(aLD, h1);
            const float aA2 = __shfl(aLA, h2), aB2 = __shfl(aLB, h2);
            const float aC2 = __shfl(aLC, h2), aD2 = __shfl(aLD, h2);

            acc0 += (fA0 * aA0 + fB0 * aB0) + (fC0 * aC0 + fD0 * aD0);
            acc1 += (fA1 * aA1 + fB1 * aB1) + (fC1 * aC1 + fD1 * aD1);
            acc2 += (fA2 * aA2 + fB2 * aB2) + (fC2 * aC2 + fD2 * aD2);
        }
        for (; i < d; ++i) {
            const int eA = edgeList[rs + i];
            const float wA = Wbuf[(size_t)(rs + i) * HEADS + hh];
            const float* frA = edge_feat + (size_t)eA * EDGE_DIM;
            const float aLA = __expf(wA - m) * rden;
            const float aA0 = __shfl(aLA, h0);
            const float aA1 = __shfl(aLA, h1);
            const float aA2 = __shfl(aLA, h2);
            acc0 += frA[c0] * aA0;
            acc1 += frA[c1] * aA1;
            if (has2) acc2 += frA[c2] * aA2;
        }
    }
    float* orow = out + (size_t)n * EDGE_DIM;
    orow[c0] = acc0;
    orow[c1] = acc1;
    if (has2) orow[c2] = acc2;
}

// ==================== fallback-only kernels (small workspace) ================
template <typename QT>
__global__ __launch_bounds__(256) void qmlp_kernel(
    const float* __restrict__ node_attrs,
    const float* __restrict__ w1, const float* __restrict__ b1,
    const float* __restrict__ w2, const float* __restrict__ b2,
    const float* __restrict__ w3, const float* __restrict__ b3,
    QT* __restrict__ qn) {
    __shared__ float xs[4][NNS];
    __shared__ float hs[4][HID];
    const int wid  = threadIdx.x >> 6;
    const int lane = threadIdx.x & 63;
    const int node = blockIdx.x * 4 + wid;
    const bool act = node < N_NODES;

    xs[wid][lane] = act ? node_attrs[(size_t)node * NNS + lane] : 0.0f;
    __syncthreads();
    float a = b1[lane];
    #pragma unroll
    for (int i = 0; i < NNS; ++i) a += xs[wid][i] * w1[i * HID + lane];
    a = silu_f(a);
    hs[wid][lane] = a;
    __syncthreads();
    float a2 = b2[lane];
    #pragma unroll
    for (int i = 0; i < HID; ++i) a2 += hs[wid][i] * w2[i * HID + lane];
    a2 = silu_f(a2);
    __syncthreads();
    xs[wid][lane] = a2;
    __syncthreads();
    if (act) {
        #pragma unroll 1
        for (int j8 = 0; j8 < 8; ++j8) {
            const int col = j8 * 64 + lane;
            float acc = b3[col];
            #pragma unroll
            for (int i = 0; i < HID; ++i) acc += xs[wid][i] * w3[i * OUTD + col];
            storeQ(qn + (size_t)node * OUTD + col, acc);
        }
    }
}

__global__ __launch_bounds__(256) void init_kernel(float* __restrict__ out,
                                                   float* __restrict__ denom,
                                                   unsigned* __restrict__ segmax) {
    int t = blockIdx.x * 256 + threadIdx.x;
    if (t < N_NODES * EDGE_DIM) out[t] = 0.0f;
    if (t < N_NODES * HEADS) {
        denom[t]  = 0.0f;
        segmax[t] = 0u;
    }
}

template <typename QT>
__global__ __launch_bounds__(256) void kmlp_kernel(
    const int* __restrict__ center, const float* __restrict__ edge_feat,
    const float* __restrict__ w1, const float* __restrict__ b1,
    const float* __restrict__ w2, const float* __restrict__ b2,
    const float* __restrict__ w3, const float* __restrict__ b3,
    const QT* __restrict__ qn, float* __restrict__ Wbuf,
    unsigned* __restrict__ segmax) {
    const int e = blockIdx.x * 256 + threadIdx.x;
    if (e >= N_EDGES) return;
    const int c = center[e];
    float x[NES];
    const float4* ef4 = reinterpret_cast<const float4*>(edge_feat + (size_t)e * EDGE_DIM);
    #pragma unroll
    for (int i = 0; i < NES / 4; ++i) {
        float4 t = ef4[i];
        x[4*i+0] = t.x; x[4*i+1] = t.y; x[4*i+2] = t.z; x[4*i+3] = t.w;
    }
    float h1[HID];
    #pragma unroll
    for (int j = 0; j < HID; ++j) {
        float a = 0.f;
        #pragma unroll
        for (int i = 0; i < NES; ++i) a += x[i] * w1[i * HID + j];
        h1[j] = silu_f(b1[j] + a);
    }
    float h2[HID];
    #pragma unroll
    for (int j = 0; j < HID; ++j) {
        float a = 0.f;
        #pragma unroll
        for (int i = 0; i < HID; ++i) a += h1[i] * w2[i * HID + j];
        h2[j] = silu_f(b2[j] + a);
    }
    const QT* q = qn + (size_t)c * OUTD;
    #pragma unroll 1
    for (int h = 0; h < HEADS; ++h) {
        float wacc = 0.0f;
        #pragma unroll 1
        for (int jj = 0; jj < HEAD_DIM; ++jj) {
            const int j = h * HEAD_DIM + jj;
            float a = 0.f;
            #pragma unroll
            for (int i = 0; i < HID; ++i) a += h2[i] * w3[i * OUTD + j];
            wacc += (b3[j] + a) * loadQ(q + j);
        }
        const float Wv = wacc * ISQRTD;
        Wbuf[(size_t)e * HEADS + h] = Wv;
        atomicMax(&segmax[c * HEADS + h], fenc(Wv));
    }
}

__global__ __launch_bounds__(256) void ex_denom_kernel(
    const int* __restrict__ center, const unsigned* __restrict__ segmax,
    float* __restrict__ Wbuf, float* __restrict__ denom) {
    const int t = blockIdx.x * 256 + threadIdx.x;
    if (t >= N_EDGES * HEADS) return;
    const int e = t >> 4;
    const int h = t & 15;
    const int c = center[e];
    const float m  = fdec(segmax[c * HEADS + h]);
    const float ex = __expf(Wbuf[t] - m);
    Wbuf[t] = ex;
    atomicAdd(&denom[c * HEADS + h], ex);
}

__global__ __launch_bounds__(256) void attn_kernel(
    const int* __restrict__ center, float* __restrict__ Wbuf,
    const float* __restrict__ denom) {
    const int t = blockIdx.x * 256 + threadIdx.x;
    if (t >= N_EDGES * HEADS) return;
    const int e = t >> 4;
    const int h = t & 15;
    Wbuf[t] = Wbuf[t] / denom[center[e] * HEADS + h];
}

__global__ __launch_bounds__(256) void scatter4_kernel(
    const int* __restrict__ center, const float* __restrict__ edge_feat,
    const float* __restrict__ attn, float* __restrict__ out) {
    const int t = blockIdx.x * 256 + threadIdx.x;
    if (t >= N_EDGES * (EDGE_DIM / 4)) return;
    const int e  = t / (EDGE_DIM / 4);
    const int cg = t - e * (EDGE_DIM / 4);
    const int c  = center[e];
    const float4 f = *(const float4*)(edge_feat + (size_t)e * EDGE_DIM + cg * 4);
    const float* arow = attn + (size_t)e * HEADS;
    const float vals[4] = {f.x, f.y, f.z, f.w};
    #pragma unroll
    for (int k = 0; k < 4; ++k) {
        const int col = cg * 4 + k;
        const int h = headOf(col);
        atomicAdd(out + (size_t)c * EDGE_DIM + col, vals[k] * arow[h]);
    }
}

extern "C" void kernel_launch(void* const* d_in, const int* in_sizes, int n_in,
                              void* d_out, int out_size, void* d_ws, size_t ws_size,
                              hipStream_t stream) {
    const int*   edge_index = (const int*)d_in[0];
    const float* edge_feat  = (const float*)d_in[1];
    const float* node_attrs = (const float*)d_in[2];
    const float* q_w1 = (const float*)d_in[3];
    const float* q_b1 = (const float*)d_in[4];
    const float* q_w2 = (const float*)d_in[5];
    const float* q_b2 = (const float*)d_in[6];
    const float* q_w3 = (const float*)d_in[7];
    const float* q_b3 = (const float*)d_in[8];
    const float* k_w1 = (const float*)d_in[9];
    const float* k_b1 = (const float*)d_in[10];
    const float* k_w2 = (const float*)d_in[11];
    const float* k_b2 = (const float*)d_in[12];
    const float* k_w3 = (const float*)d_in[13];
    const float* k_b3 = (const float*)d_in[14];
    const int* center = edge_index;
    float* out = (float*)d_out;

    const size_t szP   = (size_t)N_NODES * HID * HEADS * sizeof(float);  // 204.8 MB
    const size_t szH2  = (size_t)N_NODES * HID * sizeof(float);          //  12.8 MB
    const size_t szS   = (size_t)N_NODES * HEADS * sizeof(float);        //   3.2 MB
    const size_t szW   = (size_t)N_EDGES * HEADS * sizeof(float);        //  25.6 MB
    const size_t szM   = (size_t)HID * HID * HEADS * sizeof(float);      // 256 KB
    const size_t szMisc= (1024 + 1024 + 64 + NES * HID + HID * HID) * sizeof(float);
    const size_t szCSR = ((size_t)4 * N_NODES + N_NODES + 1 + 256 + 2 * N_EDGES) * sizeof(int);

    const int h2qGrid     = (N_NODES + 3) / 4;              // 12500
    const dim3 papGrid((N_NODES + NPB_A - 1) / NPB_A, 4);   // (782, 4)
    const int edgeGrid    = (N_EDGES + 255) / 256;
    const int wpassGrid   = (N_EDGES + 127) / 128;          // 3125
    const int nodeGrid256 = (N_NODES + 255) / 256;
    const int gatherGrid  = (N_NODES + 3) / 4;
    const int ehGrid      = (N_EDGES * HEADS + 255) / 256;

    const size_t need = szP + szH2 + szS + szW + szM + szMisc + szCSR + 4096;

    if (ws_size >= need) {
        char* p = (char*)d_ws;
        float* Pn    = (float*)p;  p += szP;
        float* h2buf = (float*)p;  p += szH2;
        float* Sn    = (float*)p;  p += szS;
        float* Wbuf  = (float*)p;  p += szW;
        float* Mmat  = (float*)p;  p += szM;
        float* C0    = (float*)p;  p += 1024 * sizeof(float);
        float* Mb    = (float*)p;  p += 1024 * sizeof(float);
        float* c1v   = (float*)p;  p += 64 * sizeof(float);
        float* w1T   = (float*)p;  p += NES * HID * sizeof(float);
        float* w2T   = (float*)p;  p += HID * HID * sizeof(float);
        int* counts   = (int*)p;
        int* incl     = counts + N_NODES;
        int* rowStart = incl + N_NODES;          // N_NODES+1
        int* cursor   = rowStart + N_NODES + 1;
        int* blockSums= cursor + N_NODES;
        int* edgeList = blockSums + 256;
        int* nodeOf   = edgeList + N_EDGES;

        prep_kernel<<<16, 256, 0, stream>>>(k_w1, k_w2, w1T, w2T);
        mbuild_kernel<<<265, 256, 0, stream>>>(q_w3, q_b3, k_w3, k_b3, Mmat, C0, Mb, c1v);
        h2q_kernel<<<h2qGrid, 256, 0, stream>>>(
            node_attrs, q_w1, q_b1, q_w2, q_b2, Mb, c1v, h2buf, Sn);
        papply_kernel<<<papGrid, 256, 0, stream>>>(h2buf, Mmat, C0, Pn);

        zero_counts_kernel<<<nodeGrid256, 256, 0, stream>>>(counts);
        hist_kernel<<<edgeGrid, 256, 0, stream>>>(center, counts);
        scan1_kernel<<<NSB, SCAN_B, 0, stream>>>(counts, incl, blockSums);
        scan2_kernel<<<1, 64, 0, stream>>>(blockSums);
        scan3_kernel<<<NSB, SCAN_B, 0, stream>>>(counts, incl, blockSums, rowStart, cursor);
        fill_kernel<<<edgeGrid, 256, 0, stream>>>(center, cursor, edgeList, nodeOf);

        wpass8_kernel<<<wpassGrid, 256, 0, stream>>>(
            edgeList, nodeOf, edge_feat, w1T, k_b1, w2T, k_b2, Pn, Sn, Wbuf);
        gather4_kernel<<<gatherGrid, 256, 0, stream>>>(rowStart, edgeList, edge_feat, Wbuf, out);
        return;
    }

    // ---------------- fallback: atomic pipeline (small ws) -------------------
    const size_t szQ   = (size_t)N_NODES * OUTD * sizeof(float);
    char* p = (char*)d_ws;
    float*    Wbuf   = (float*)p;    p += szW;
    float*    denom  = (float*)p;    p += szS;
    unsigned* segmax = (unsigned*)p; p += szS;
    const size_t fbase = (size_t)(p - (char*)d_ws);
    const bool qf32 = ws_size >= fbase + szQ;

    const int initGrid    = (N_NODES * EDGE_DIM + 255) / 256;
    const int scatterGrid = (N_EDGES * (EDGE_DIM / 4) + 255) / 256;
    const int qmlpGrid    = (N_NODES + 3) / 4;

    init_kernel<<<initGrid, 256, 0, stream>>>(out, denom, segmax);
    if (qf32) {
        float* qn = (float*)p;
        qmlp_kernel<float><<<qmlpGrid, 256, 0, stream>>>(
            node_attrs, q_w1, q_b1, q_w2, q_b2, q_w3, q_b3, qn);
        kmlp_kernel<float><<<edgeGrid, 256, 0, stream>>>(
            center, edge_feat, k_w1, k_b1, k_w2, k_b2, k_w3, k_b3, qn, Wbuf, segmax);
    } else {
        __hip_bfloat16* qn = (__hip_bfloat16*)p;
        qmlp_kernel<__hip_bfloat16><<<qmlpGrid, 256, 0, stream>>>(
            node_attrs, q_w1, q_b1, q_w2, q_b2, q_w3, q_b3, qn);
        kmlp_kernel<__hip_bfloat16><<<edgeGrid, 256, 0, stream>>>(
            center, edge_feat, k_w1, k_b1, k_w2, k_b2, k_w3, k_b3, qn, Wbuf, segmax);
    }
    ex_denom_kernel<<<ehGrid, 256, 0, stream>>>(center, segmax, Wbuf, denom);
    attn_kernel<<<ehGrid, 256, 0, stream>>>(center, Wbuf, denom);
    scatter4_kernel<<<scatterGrid, 256, 0, stream>>>(center, edge_feat, Wbuf, out);
}

// Round 15
// 559.862 us; speedup vs baseline: 1.6100x; 1.6100x over previous
//
#include <hip/hip_runtime.h>
#include <hip/hip_bf16.h>

constexpr int N_NODES  = 50000;
constexpr int N_EDGES  = 400000;
constexpr int EDGE_DIM = 144;
constexpr int HEADS    = 16;
constexpr int HEAD_DIM = 32;
constexpr int OUTD     = 512;   // HEADS*HEAD_DIM
constexpr int HID      = 64;
constexpr int NES      = 16;
constexpr int NNS      = 64;
constexpr int SCAN_B   = 512;
constexpr int NSB      = (N_NODES + SCAN_B - 1) / SCAN_B;   // 98
constexpr int NPB_A    = 64;    // nodes per block, papply
#define ISQRTD 0.17677669529663687f

__device__ __forceinline__ float silu_f(float x) {
    return x / (1.0f + __expf(-x));
}

__device__ __forceinline__ unsigned fenc(float f) {
    unsigned u = __float_as_uint(f);
    return (u & 0x80000000u) ? ~u : (u | 0x80000000u);
}
__device__ __forceinline__ float fdec(unsigned m) {
    unsigned u = (m & 0x80000000u) ? (m ^ 0x80000000u) : ~m;
    return __uint_as_float(u);
}

__device__ __forceinline__ int headOf(int col) {
    return (col < 16) ? col : ((col < 64) ? (col - 16) / 3 : (col - 64) / 5);
}

__device__ __forceinline__ void storeQ(float* p, float v) { *p = v; }
__device__ __forceinline__ void storeQ(__hip_bfloat16* p, float v) { *p = __float2bfloat16(v); }
__device__ __forceinline__ float loadQ(const float* p) { return *p; }
__device__ __forceinline__ float loadQ(const __hip_bfloat16* p) { return __bfloat162float(*p); }

// -------- prep: transpose k_w1 (16x64 -> 64x16) and k_w2 (64x64) -------------
__global__ __launch_bounds__(256) void prep_kernel(
    const float* __restrict__ w1, const float* __restrict__ w2,
    float* __restrict__ w1T, float* __restrict__ w2T) {
    int t = blockIdx.x * 256 + threadIdx.x;
    if (t < NES * HID) {
        int i = t / HID, j = t % HID;
        w1T[j * NES + i] = w1[t];
    }
    if (t < HID * HID) {
        int i = t / HID, j = t % HID;
        w2T[j * HID + i] = w2[t];
    }
}

// -------- mbuild: M[hg][i][j][hl], C0[hg][i][hl], Mb[h][j], c1[h] ------------
__global__ __launch_bounds__(256) void mbuild_kernel(
    const float* __restrict__ qw3, const float* __restrict__ qb3,
    const float* __restrict__ kw3, const float* __restrict__ kb3,
    float* __restrict__ M, float* __restrict__ C0,
    float* __restrict__ Mb, float* __restrict__ c1) {
    const int b = blockIdx.x, t = threadIdx.x;
    if (b < 256) {                     // M: 65536 entries
        const int o  = b * 256 + t;
        const int hl = o & 3, j = (o >> 2) & 63, i = (o >> 8) & 63, hg = o >> 14;
        const int h  = hg * 4 + hl;
        const float* ka = kw3 + (size_t)i * OUTD + h * HEAD_DIM;
        const float* qa = qw3 + (size_t)j * OUTD + h * HEAD_DIM;
        float s = 0.f;
        #pragma unroll
        for (int d = 0; d < HEAD_DIM; ++d) s += ka[d] * qa[d];
        M[o] = s;
    } else if (b < 260) {              // C0: 1024 entries, layout [hg][i][hl]
        const int o  = (b - 256) * 256 + t;
        const int hl = o & 3, i = (o >> 2) & 63, hg = o >> 8;
        const int h  = hg * 4 + hl;
        float s = 0.f;
        #pragma unroll
        for (int d = 0; d < HEAD_DIM; ++d)
            s += kw3[(size_t)i * OUTD + h * HEAD_DIM + d] * qb3[h * HEAD_DIM + d];
        C0[o] = s;
    } else if (b < 264) {              // Mb: [h][j]
        const int o = (b - 260) * 256 + t;
        const int h = o >> 6, j = o & 63;
        float s = 0.f;
        #pragma unroll
        for (int d = 0; d < HEAD_DIM; ++d)
            s += kb3[h * HEAD_DIM + d] * qw3[(size_t)j * OUTD + h * HEAD_DIM + d];
        Mb[o] = s;
    } else {                           // c1: 16
        if (t < HEADS) {
            float s = 0.f;
            #pragma unroll
            for (int d = 0; d < HEAD_DIM; ++d)
                s += kb3[t * HEAD_DIM + d] * qb3[t * HEAD_DIM + d];
            c1[t] = s;
        }
    }
}

// -------- h2q: Q-MLP layers 1-2 per node + Sn = h2.Mb + c1 -------------------
__global__ __launch_bounds__(256) void h2q_kernel(
    const float* __restrict__ node_attrs,
    const float* __restrict__ w1, const float* __restrict__ b1,
    const float* __restrict__ w2, const float* __restrict__ b2,
    const float* __restrict__ Mb, const float* __restrict__ c1,
    float* __restrict__ h2buf, float* __restrict__ Sn) {
    __shared__ float xs[4][NNS];
    __shared__ float h1s[4][HID];
    __shared__ float h2s[4][HID];
    __shared__ float Mbs[HEADS][65];
    __shared__ float c1s[HEADS];
    const int t = threadIdx.x, wid = t >> 6, lane = t & 63;
    for (int o = t; o < HEADS * HID; o += 256) Mbs[o >> 6][o & 63] = Mb[o];
    if (t < HEADS) c1s[t] = c1[t];

    const int n = blockIdx.x * 4 + wid;
    const bool act = n < N_NODES;
    xs[wid][lane] = act ? node_attrs[(size_t)n * NNS + lane] : 0.0f;
    __syncthreads();

    float a = b1[lane];
    #pragma unroll
    for (int i = 0; i < NNS; ++i) a += xs[wid][i] * w1[i * HID + lane];
    h1s[wid][lane] = silu_f(a);
    __syncthreads();

    float a2 = b2[lane];
    #pragma unroll
    for (int i = 0; i < HID; ++i) a2 += h1s[wid][i] * w2[i * HID + lane];
    const float h2v = silu_f(a2);
    h2s[wid][lane] = h2v;
    if (act) h2buf[(size_t)n * HID + lane] = h2v;
    __syncthreads();

    const int h = lane & 15, q = lane >> 4;
    float s = 0.f;
    #pragma unroll
    for (int jj = 0; jj < 16; ++jj) s += h2s[wid][q * 16 + jj] * Mbs[h][q * 16 + jj];
    s += __shfl_xor(s, 16);
    s += __shfl_xor(s, 32);
    if (act && lane < HEADS) Sn[(size_t)n * HEADS + lane] = s + c1s[lane];
}

// -------- papply: P[n][hg][j][hl] = h2.Mreg + C0 (persistent M regs) ---------
__global__ __launch_bounds__(256) void papply_kernel(
    const float* __restrict__ h2buf, const float* __restrict__ M,
    const float* __restrict__ C0, float* __restrict__ Pn) {
    const int t  = threadIdx.x;
    const int hg = blockIdx.y;

    float Mreg[HID];
    const float* msrc = M + (size_t)hg * 16384 + (t >> 2) * 256 + (t & 3);
    #pragma unroll
    for (int j = 0; j < HID; ++j) Mreg[j] = msrc[j * 4];
    const float c0 = C0[hg * 256 + t];

    __shared__ float h2s[4][HID];
    const int n0 = blockIdx.x * NPB_A;
    #pragma unroll 1
    for (int s4 = 0; s4 < NPB_A / 4; ++s4) {
        const int nb = n0 + s4 * 4;
        const int nl = nb + (t >> 6);
        const float v = (nl < N_NODES) ? h2buf[(size_t)nl * HID + (t & 63)] : 0.f;
        __syncthreads();
        h2s[t >> 6][t & 63] = v;
        __syncthreads();
        #pragma unroll 1
        for (int mm = 0; mm < 4; ++mm) {
            const int n = nb + mm;
            if (n >= N_NODES) break;
            float acc0 = c0, acc1 = 0.f;
            #pragma unroll
            for (int j = 0; j < HID; j += 2) {
                acc0 += h2s[mm][j]     * Mreg[j];
                acc1 += h2s[mm][j + 1] * Mreg[j + 1];
            }
            Pn[(size_t)n * 1024 + hg * 256 + t] = acc0 + acc1;
        }
    }
}

// -------- CSR build ----------------------------------------------------------
__global__ __launch_bounds__(256) void zero_counts_kernel(int* __restrict__ counts) {
    int t = blockIdx.x * 256 + threadIdx.x;
    if (t < N_NODES) counts[t] = 0;
}
__global__ __launch_bounds__(256) void hist_kernel(const int* __restrict__ center,
                                                   int* __restrict__ counts) {
    int e = blockIdx.x * 256 + threadIdx.x;
    if (e < N_EDGES) atomicAdd(&counts[center[e]], 1);
}
__global__ __launch_bounds__(SCAN_B) void scan1_kernel(
    const int* __restrict__ counts, int* __restrict__ incl, int* __restrict__ blockSums) {
    __shared__ int sm[SCAN_B];
    const int gid = blockIdx.x * SCAN_B + threadIdx.x;
    sm[threadIdx.x] = (gid < N_NODES) ? counts[gid] : 0;
    __syncthreads();
    #pragma unroll 1
    for (int off = 1; off < SCAN_B; off <<= 1) {
        int t = (threadIdx.x >= off) ? sm[threadIdx.x - off] : 0;
        __syncthreads();
        sm[threadIdx.x] += t;
        __syncthreads();
    }
    if (gid < N_NODES) incl[gid] = sm[threadIdx.x];
    if (threadIdx.x == SCAN_B - 1) blockSums[blockIdx.x] = sm[threadIdx.x];
}
__global__ void scan2_kernel(int* __restrict__ blockSums) {
    if (threadIdx.x == 0 && blockIdx.x == 0) {
        int run = 0;
        for (int i = 0; i < NSB; ++i) { int t = blockSums[i]; blockSums[i] = run; run += t; }
    }
}
__global__ __launch_bounds__(SCAN_B) void scan3_kernel(
    const int* __restrict__ counts, const int* __restrict__ incl,
    const int* __restrict__ blockSums, int* __restrict__ rowStart,
    int* __restrict__ cursor) {
    const int gid = blockIdx.x * SCAN_B + threadIdx.x;
    if (gid < N_NODES) {
        const int excl = incl[gid] - counts[gid] + blockSums[blockIdx.x];
        rowStart[gid] = excl;
        cursor[gid]   = excl;
    }
    if (gid == 0) rowStart[N_NODES] = N_EDGES;
}
__global__ __launch_bounds__(256) void fill_kernel(const int* __restrict__ center,
                                                   int* __restrict__ cursor,
                                                   int* __restrict__ edgeList,
                                                   int* __restrict__ nodeOf) {
    int e = blockIdx.x * 256 + threadIdx.x;
    if (e < N_EDGES) {
        const int c = center[e];
        int pos = atomicAdd(&cursor[c], 1);
        edgeList[pos] = e;
        nodeOf[pos]   = c;
    }
}

// -------- W-pass v9: fused, 4-j register blocking (1 h1 read -> 4 FMAs) ------
__global__ __launch_bounds__(256, 2) void wpass9_kernel(
    const int* __restrict__ edgeList, const int* __restrict__ nodeOf,
    const float* __restrict__ edge_feat,
    const float* __restrict__ w1T, const float* __restrict__ b1,
    const float* __restrict__ w2T, const float* __restrict__ b2,
    const float* __restrict__ Pn, const float* __restrict__ Sn,
    float* __restrict__ Wbuf) {
    const int p = blockIdx.x * 256 + threadIdx.x;
    if (p >= N_EDGES) return;
    const int e = edgeList[p];
    const int c = nodeOf[p];

    float x[NES];
    const float4* ef4 = reinterpret_cast<const float4*>(edge_feat + (size_t)e * EDGE_DIM);
    #pragma unroll
    for (int i = 0; i < NES / 4; ++i) {
        float4 t = ef4[i];
        x[4*i+0] = t.x; x[4*i+1] = t.y; x[4*i+2] = t.z; x[4*i+3] = t.w;
    }

    // layer 1: quad accumulators
    float h1[HID];
    #pragma unroll
    for (int j = 0; j < HID; ++j) {
        float a0 = 0.f, a1 = 0.f, a2 = 0.f, a3 = 0.f;
        const float* wr = w1T + j * NES;
        #pragma unroll
        for (int i = 0; i < NES; i += 4) {
            a0 += x[i + 0] * wr[i + 0];
            a1 += x[i + 1] * wr[i + 1];
            a2 += x[i + 2] * wr[i + 2];
            a3 += x[i + 3] * wr[i + 3];
        }
        h1[j] = silu_f(b1[j] + ((a0 + a1) + (a2 + a3)));
    }

    // W accumulators seeded with Sn
    float wacc[HEADS];
    {
        const float4* s4 = (const float4*)(Sn + (size_t)c * HEADS);
        #pragma unroll
        for (int k = 0; k < 4; ++k) {
            float4 v = s4[k];
            wacc[4*k+0] = v.x; wacc[4*k+1] = v.y; wacc[4*k+2] = v.z; wacc[4*k+3] = v.w;
        }
    }

    // layer 2 fused with P-dot, 4-j blocking: each h1[i] read feeds 4 chains
    const float* prow = Pn + (size_t)c * 1024;
    #pragma unroll 1
    for (int j4 = 0; j4 < HID / 4; ++j4) {
        const int j = j4 * 4;
        const float* w0 = w2T + (j + 0) * HID;
        const float* w1r = w2T + (j + 1) * HID;
        const float* w2r = w2T + (j + 2) * HID;
        const float* w3r = w2T + (j + 3) * HID;
        float a0 = b2[j], a1 = b2[j + 1], a2 = b2[j + 2], a3 = b2[j + 3];
        #pragma unroll
        for (int i = 0; i < HID; ++i) {
            const float hv = h1[i];
            a0 += hv * w0[i];
            a1 += hv * w1r[i];
            a2 += hv * w2r[i];
            a3 += hv * w3r[i];
        }
        const float h20 = silu_f(a0);
        const float h21 = silu_f(a1);
        const float h22 = silu_f(a2);
        const float h23 = silu_f(a3);
        #pragma unroll
        for (int hg = 0; hg < 4; ++hg) {
            const float4 p0 = *(const float4*)(prow + hg * 256 + (j + 0) * 4);
            const float4 p1 = *(const float4*)(prow + hg * 256 + (j + 1) * 4);
            const float4 p2 = *(const float4*)(prow + hg * 256 + (j + 2) * 4);
            const float4 p3 = *(const float4*)(prow + hg * 256 + (j + 3) * 4);
            wacc[hg*4+0] += h20 * p0.x + h21 * p1.x + h22 * p2.x + h23 * p3.x;
            wacc[hg*4+1] += h20 * p0.y + h21 * p1.y + h22 * p2.y + h23 * p3.y;
            wacc[hg*4+2] += h20 * p0.z + h21 * p1.z + h22 * p2.z + h23 * p3.z;
            wacc[hg*4+3] += h20 * p0.w + h21 * p1.w + h22 * p2.w + h23 * p3.w;
        }
    }

    float4* wrow = (float4*)(Wbuf + (size_t)p * HEADS);
    #pragma unroll
    for (int k = 0; k < 4; ++k) {
        wrow[k] = make_float4(wacc[4*k+0] * ISQRTD, wacc[4*k+1] * ISQRTD,
                              wacc[4*k+2] * ISQRTD, wacc[4*k+3] * ISQRTD);
    }
}

// -------- node gather v4: softmax + weighted sum, 4 rows in flight -----------
__global__ __launch_bounds__(256) void gather4_kernel(
    const int* __restrict__ rowStart, const int* __restrict__ edgeList,
    const float* __restrict__ edge_feat, const float* __restrict__ Wbuf,
    float* __restrict__ out) {
    const int wid  = threadIdx.x >> 6;
    const int lane = threadIdx.x & 63;
    const int n = blockIdx.x * 4 + wid;
    if (n >= N_NODES) return;
    const int rs = rowStart[n];
    const int d  = rowStart[n + 1] - rs;

    const int c0 = lane, c1 = lane + 64, c2 = lane + 128;
    const int h0 = headOf(c0);
    const int h1 = headOf(c1);
    const int h2 = (c2 < EDGE_DIM) ? headOf(c2) : 0;
    const bool has2 = (c2 < EDGE_DIM);

    float acc0 = 0.f, acc1 = 0.f, acc2 = 0.f;
    if (d > 0) {
        const int hh  = lane & 15;
        const int sub = lane >> 4;
        float m = -3.0e38f;
        for (int i = sub; i < d; i += 4)
            m = fmaxf(m, Wbuf[(size_t)(rs + i) * HEADS + hh]);
        m = fmaxf(m, __shfl_xor(m, 16));
        m = fmaxf(m, __shfl_xor(m, 32));
        float s = 0.f;
        for (int i = sub; i < d; i += 4)
            s += __expf(Wbuf[(size_t)(rs + i) * HEADS + hh] - m);
        s += __shfl_xor(s, 16);
        s += __shfl_xor(s, 32);
        const float rden = 1.0f / s;

        int i = 0;
        for (; i + 4 <= d; i += 4) {
            const int eA = edgeList[rs + i + 0];
            const int eB = edgeList[rs + i + 1];
            const int eC = edgeList[rs + i + 2];
            const int eD = edgeList[rs + i + 3];
            const float wA = Wbuf[(size_t)(rs + i + 0) * HEADS + hh];
            const float wB = Wbuf[(size_t)(rs + i + 1) * HEADS + hh];
            const float wC = Wbuf[(size_t)(rs + i + 2) * HEADS + hh];
            const float wD = Wbuf[(size_t)(rs + i + 3) * HEADS + hh];
            const float* frA = edge_feat + (size_t)eA * EDGE_DIM;
            const float* frB = edge_feat + (size_t)eB * EDGE_DIM;
            const float* frC = edge_feat + (size_t)eC * EDGE_DIM;
            const float* frD = edge_feat + (size_t)eD * EDGE_DIM;
            const float fA0 = frA[c0], fB0 = frB[c0], fC0 = frC[c0], fD0 = frD[c0];
            const float fA1 = frA[c1], fB1 = frB[c1], fC1 = frC[c1], fD1 = frD[c1];
            const float fA2 = has2 ? frA[c2] : 0.f;
            const float fB2 = has2 ? frB[c2] : 0.f;
            const float fC2 = has2 ? frC[c2] : 0.f;
            const float fD2 = has2 ? frD[c2] : 0.f;

            const float aLA = __expf(wA - m) * rden;
            const float aLB = __expf(wB - m) * rden;
            const float aLC = __expf(wC - m) * rden;
            const float aLD = __expf(wD - m) * rden;
            const float aA0 = __shfl(aLA, h0), aB0 = __shfl(aLB, h0);
            const float aC0 = __shfl(aLC, h0), aD0 = __shfl(aLD, h0);
            const float aA1 = __shfl(aLA, h1), aB1 = __shfl(aLB, h1);
            const float aC1 = __shfl(aLC, h1), aD1 = __shfl(aLD, h1);
            const float aA2 = __shfl(aLA, h2), aB2 = __shfl(aLB, h2);
            const float aC2 = __shfl(aLC, h2), aD2 = __shfl(aLD, h2);

            acc0 += (fA0 * aA0 + fB0 * aB0) + (fC0 * aC0 + fD0 * aD0);
            acc1 += (fA1 * aA1 + fB1 * aB1) + (fC1 * aC1 + fD1 * aD1);
            acc2 += (fA2 * aA2 + fB2 * aB2) + (fC2 * aC2 + fD2 * aD2);
        }
        for (; i < d; ++i) {
            const int eA = edgeList[rs + i];
            const float wA = Wbuf[(size_t)(rs + i) * HEADS + hh];
            const float* frA = edge_feat + (size_t)eA * EDGE_DIM;
            const float aLA = __expf(wA - m) * rden;
            const float aA0 = __shfl(aLA, h0);
            const float aA1 = __shfl(aLA, h1);
            const float aA2 = __shfl(aLA, h2);
            acc0 += frA[c0] * aA0;
            acc1 += frA[c1] * aA1;
            if (has2) acc2 += frA[c2] * aA2;
        }
    }
    float* orow = out + (size_t)n * EDGE_DIM;
    orow[c0] = acc0;
    orow[c1] = acc1;
    if (has2) orow[c2] = acc2;
}

// ==================== fallback-only kernels (small workspace) ================
template <typename QT>
__global__ __launch_bounds__(256) void qmlp_kernel(
    const float* __restrict__ node_attrs,
    const float* __restrict__ w1, const float* __restrict__ b1,
    const float* __restrict__ w2, const float* __restrict__ b2,
    const float* __restrict__ w3, const float* __restrict__ b3,
    QT* __restrict__ qn) {
    __shared__ float xs[4][NNS];
    __shared__ float hs[4][HID];
    const int wid  = threadIdx.x >> 6;
    const int lane = threadIdx.x & 63;
    const int node = blockIdx.x * 4 + wid;
    const bool act = node < N_NODES;

    xs[wid][lane] = act ? node_attrs[(size_t)node * NNS + lane] : 0.0f;
    __syncthreads();
    float a = b1[lane];
    #pragma unroll
    for (int i = 0; i < NNS; ++i) a += xs[wid][i] * w1[i * HID + lane];
    a = silu_f(a);
    hs[wid][lane] = a;
    __syncthreads();
    float a2 = b2[lane];
    #pragma unroll
    for (int i = 0; i < HID; ++i) a2 += hs[wid][i] * w2[i * HID + lane];
    a2 = silu_f(a2);
    __syncthreads();
    xs[wid][lane] = a2;
    __syncthreads();
    if (act) {
        #pragma unroll 1
        for (int j8 = 0; j8 < 8; ++j8) {
            const int col = j8 * 64 + lane;
            float acc = b3[col];
            #pragma unroll
            for (int i = 0; i < HID; ++i) acc += xs[wid][i] * w3[i * OUTD + col];
            storeQ(qn + (size_t)node * OUTD + col, acc);
        }
    }
}

__global__ __launch_bounds__(256) void init_kernel(float* __restrict__ out,
                                                   float* __restrict__ denom,
                                                   unsigned* __restrict__ segmax) {
    int t = blockIdx.x * 256 + threadIdx.x;
    if (t < N_NODES * EDGE_DIM) out[t] = 0.0f;
    if (t < N_NODES * HEADS) {
        denom[t]  = 0.0f;
        segmax[t] = 0u;
    }
}

template <typename QT>
__global__ __launch_bounds__(256) void kmlp_kernel(
    const int* __restrict__ center, const float* __restrict__ edge_feat,
    const float* __restrict__ w1, const float* __restrict__ b1,
    const float* __restrict__ w2, const float* __restrict__ b2,
    const float* __restrict__ w3, const float* __restrict__ b3,
    const QT* __restrict__ qn, float* __restrict__ Wbuf,
    unsigned* __restrict__ segmax) {
    const int e = blockIdx.x * 256 + threadIdx.x;
    if (e >= N_EDGES) return;
    const int c = center[e];
    float x[NES];
    const float4* ef4 = reinterpret_cast<const float4*>(edge_feat + (size_t)e * EDGE_DIM);
    #pragma unroll
    for (int i = 0; i < NES / 4; ++i) {
        float4 t = ef4[i];
        x[4*i+0] = t.x; x[4*i+1] = t.y; x[4*i+2] = t.z; x[4*i+3] = t.w;
    }
    float h1[HID];
    #pragma unroll
    for (int j = 0; j < HID; ++j) {
        float a = 0.f;
        #pragma unroll
        for (int i = 0; i < NES; ++i) a += x[i] * w1[i * HID + j];
        h1[j] = silu_f(b1[j] + a);
    }
    float h2[HID];
    #pragma unroll
    for (int j = 0; j < HID; ++j) {
        float a = 0.f;
        #pragma unroll
        for (int i = 0; i < HID; ++i) a += h1[i] * w2[i * HID + j];
        h2[j] = silu_f(b2[j] + a);
    }
    const QT* q = qn + (size_t)c * OUTD;
    #pragma unroll 1
    for (int h = 0; h < HEADS; ++h) {
        float wacc = 0.0f;
        #pragma unroll 1
        for (int jj = 0; jj < HEAD_DIM; ++jj) {
            const int j = h * HEAD_DIM + jj;
            float a = 0.f;
            #pragma unroll
            for (int i = 0; i < HID; ++i) a += h2[i] * w3[i * OUTD + j];
            wacc += (b3[j] + a) * loadQ(q + j);
        }
        const float Wv = wacc * ISQRTD;
        Wbuf[(size_t)e * HEADS + h] = Wv;
        atomicMax(&segmax[c * HEADS + h], fenc(Wv));
    }
}

__global__ __launch_bounds__(256) void ex_denom_kernel(
    const int* __restrict__ center, const unsigned* __restrict__ segmax,
    float* __restrict__ Wbuf, float* __restrict__ denom) {
    const int t = blockIdx.x * 256 + threadIdx.x;
    if (t >= N_EDGES * HEADS) return;
    const int e = t >> 4;
    const int h = t & 15;
    const int c = center[e];
    const float m  = fdec(segmax[c * HEADS + h]);
    const float ex = __expf(Wbuf[t] - m);
    Wbuf[t] = ex;
    atomicAdd(&denom[c * HEADS + h], ex);
}

__global__ __launch_bounds__(256) void attn_kernel(
    const int* __restrict__ center, float* __restrict__ Wbuf,
    const float* __restrict__ denom) {
    const int t = blockIdx.x * 256 + threadIdx.x;
    if (t >= N_EDGES * HEADS) return;
    const int e = t >> 4;
    const int h = t & 15;
    Wbuf[t] = Wbuf[t] / denom[center[e] * HEADS + h];
}

__global__ __launch_bounds__(256) void scatter4_kernel(
    const int* __restrict__ center, const float* __restrict__ edge_feat,
    const float* __restrict__ attn, float* __restrict__ out) {
    const int t = blockIdx.x * 256 + threadIdx.x;
    if (t >= N_EDGES * (EDGE_DIM / 4)) return;
    const int e  = t / (EDGE_DIM / 4);
    const int cg = t - e * (EDGE_DIM / 4);
    const int c  = center[e];
    const float4 f = *(const float4*)(edge_feat + (size_t)e * EDGE_DIM + cg * 4);
    const float* arow = attn + (size_t)e * HEADS;
    const float vals[4] = {f.x, f.y, f.z, f.w};
    #pragma unroll
    for (int k = 0; k < 4; ++k) {
        const int col = cg * 4 + k;
        const int h = headOf(col);
        atomicAdd(out + (size_t)c * EDGE_DIM + col, vals[k] * arow[h]);
    }
}

extern "C" void kernel_launch(void* const* d_in, const int* in_sizes, int n_in,
                              void* d_out, int out_size, void* d_ws, size_t ws_size,
                              hipStream_t stream) {
    const int*   edge_index = (const int*)d_in[0];
    const float* edge_feat  = (const float*)d_in[1];
    const float* node_attrs = (const float*)d_in[2];
    const float* q_w1 = (const float*)d_in[3];
    const float* q_b1 = (const float*)d_in[4];
    const float* q_w2 = (const float*)d_in[5];
    const float* q_b2 = (const float*)d_in[6];
    const float* q_w3 = (const float*)d_in[7];
    const float* q_b3 = (const float*)d_in[8];
    const float* k_w1 = (const float*)d_in[9];
    const float* k_b1 = (const float*)d_in[10];
    const float* k_w2 = (const float*)d_in[11];
    const float* k_b2 = (const float*)d_in[12];
    const float* k_w3 = (const float*)d_in[13];
    const float* k_b3 = (const float*)d_in[14];
    const int* center = edge_index;
    float* out = (float*)d_out;

    const size_t szP   = (size_t)N_NODES * HID * HEADS * sizeof(float);  // 204.8 MB
    const size_t szH2  = (size_t)N_NODES * HID * sizeof(float);          //  12.8 MB
    const size_t szS   = (size_t)N_NODES * HEADS * sizeof(float);        //   3.2 MB
    const size_t szW   = (size_t)N_EDGES * HEADS * sizeof(float);        //  25.6 MB
    const size_t szM   = (size_t)HID * HID * HEADS * sizeof(float);      // 256 KB
    const size_t szMisc= (1024 + 1024 + 64 + NES * HID + HID * HID) * sizeof(float);
    const size_t szCSR = ((size_t)4 * N_NODES + N_NODES + 1 + 256 + 2 * N_EDGES) * sizeof(int);

    const int h2qGrid     = (N_NODES + 3) / 4;              // 12500
    const dim3 papGrid((N_NODES + NPB_A - 1) / NPB_A, 4);   // (782, 4)
    const int edgeGrid    = (N_EDGES + 255) / 256;
    const int nodeGrid256 = (N_NODES + 255) / 256;
    const int gatherGrid  = (N_NODES + 3) / 4;
    const int ehGrid      = (N_EDGES * HEADS + 255) / 256;

    const size_t need = szP + szH2 + szS + szW + szM + szMisc + szCSR + 4096;

    if (ws_size >= need) {
        char* p = (char*)d_ws;
        float* Pn    = (float*)p;  p += szP;
        float* h2buf = (float*)p;  p += szH2;
        float* Sn    = (float*)p;  p += szS;
        float* Wbuf  = (float*)p;  p += szW;
        float* Mmat  = (float*)p;  p += szM;
        float* C0    = (float*)p;  p += 1024 * sizeof(float);
        float* Mb    = (float*)p;  p += 1024 * sizeof(float);
        float* c1v   = (float*)p;  p += 64 * sizeof(float);
        float* w1T   = (float*)p;  p += NES * HID * sizeof(float);
        float* w2T   = (float*)p;  p += HID * HID * sizeof(float);
        int* counts   = (int*)p;
        int* incl     = counts + N_NODES;
        int* rowStart = incl + N_NODES;          // N_NODES+1
        int* cursor   = rowStart + N_NODES + 1;
        int* blockSums= cursor + N_NODES;
        int* edgeList = blockSums + 256;
        int* nodeOf   = edgeList + N_EDGES;

        prep_kernel<<<16, 256, 0, stream>>>(k_w1, k_w2, w1T, w2T);
        mbuild_kernel<<<265, 256, 0, stream>>>(q_w3, q_b3, k_w3, k_b3, Mmat, C0, Mb, c1v);
        h2q_kernel<<<h2qGrid, 256, 0, stream>>>(
            node_attrs, q_w1, q_b1, q_w2, q_b2, Mb, c1v, h2buf, Sn);
        papply_kernel<<<papGrid, 256, 0, stream>>>(h2buf, Mmat, C0, Pn);

        zero_counts_kernel<<<nodeGrid256, 256, 0, stream>>>(counts);
        hist_kernel<<<edgeGrid, 256, 0, stream>>>(center, counts);
        scan1_kernel<<<NSB, SCAN_B, 0, stream>>>(counts, incl, blockSums);
        scan2_kernel<<<1, 64, 0, stream>>>(blockSums);
        scan3_kernel<<<NSB, SCAN_B, 0, stream>>>(counts, incl, blockSums, rowStart, cursor);
        fill_kernel<<<edgeGrid, 256, 0, stream>>>(center, cursor, edgeList, nodeOf);

        wpass9_kernel<<<edgeGrid, 256, 0, stream>>>(
            edgeList, nodeOf, edge_feat, w1T, k_b1, w2T, k_b2, Pn, Sn, Wbuf);
        gather4_kernel<<<gatherGrid, 256, 0, stream>>>(rowStart, edgeList, edge_feat, Wbuf, out);
        return;
    }

    // ---------------- fallback: atomic pipeline (small ws) -------------------
    const size_t szQ   = (size_t)N_NODES * OUTD * sizeof(float);
    char* p = (char*)d_ws;
    float*    Wbuf   = (float*)p;    p += szW;
    float*    denom  = (float*)p;    p += szS;
    unsigned* segmax = (unsigned*)p; p += szS;
    const size_t fbase = (size_t)(p - (char*)d_ws);
    const bool qf32 = ws_size >= fbase + szQ;

    const int initGrid    = (N_NODES * EDGE_DIM + 255) / 256;
    const int scatterGrid = (N_EDGES * (EDGE_DIM / 4) + 255) / 256;
    const int qmlpGrid    = (N_NODES + 3) / 4;

    init_kernel<<<initGrid, 256, 0, stream>>>(out, denom, segmax);
    if (qf32) {
        float* qn = (float*)p;
        qmlp_kernel<float><<<qmlpGrid, 256, 0, stream>>>(
            node_attrs, q_w1, q_b1, q_w2, q_b2, q_w3, q_b3, qn);
        kmlp_kernel<float><<<edgeGrid, 256, 0, stream>>>(
            center, edge_feat, k_w1, k_b1, k_w2, k_b2, k_w3, k_b3, qn, Wbuf, segmax);
    } else {
        __hip_bfloat16* qn = (__hip_bfloat16*)p;
        qmlp_kernel<__hip_bfloat16><<<qmlpGrid, 256, 0, stream>>>(
            node_attrs, q_w1, q_b1, q_w2, q_b2, q_w3, q_b3, qn);
        kmlp_kernel<__hip_bfloat16><<<edgeGrid, 256, 0, stream>>>(
            center, edge_feat, k_w1, k_b1, k_w2, k_b2, k_w3, k_b3, qn, Wbuf, segmax);
    }
    ex_denom_kernel<<<ehGrid, 256, 0, stream>>>(center, segmax, Wbuf, denom);
    attn_kernel<<<ehGrid, 256, 0, stream>>>(center, Wbuf, denom);
    scatter4_kernel<<<scatterGrid, 256, 0, stream>>>(center, edge_feat, Wbuf, out);
}

// Round 16
// 476.515 us; speedup vs baseline: 1.8916x; 1.1749x over previous
//
#include <hip/hip_runtime.h>
#include <hip/hip_bf16.h>

constexpr int N_NODES  = 50000;
constexpr int N_EDGES  = 400000;
constexpr int EDGE_DIM = 144;
constexpr int HEADS    = 16;
constexpr int HEAD_DIM = 32;
constexpr int OUTD     = 512;   // HEADS*HEAD_DIM
constexpr int HID      = 64;
constexpr int NES      = 16;
constexpr int NNS      = 64;
constexpr int SCAN_B   = 512;
constexpr int NSB      = (N_NODES + SCAN_B - 1) / SCAN_B;   // 98
constexpr int NPB_A    = 64;    // nodes per block, papply
#define ISQRTD 0.17677669529663687f

__device__ __forceinline__ float silu_f(float x) {
    return x / (1.0f + __expf(-x));
}

__device__ __forceinline__ unsigned fenc(float f) {
    unsigned u = __float_as_uint(f);
    return (u & 0x80000000u) ? ~u : (u | 0x80000000u);
}
__device__ __forceinline__ float fdec(unsigned m) {
    unsigned u = (m & 0x80000000u) ? (m ^ 0x80000000u) : ~m;
    return __uint_as_float(u);
}

__device__ __forceinline__ int headOf(int col) {
    return (col < 16) ? col : ((col < 64) ? (col - 16) / 3 : (col - 64) / 5);
}

__device__ __forceinline__ void storeQ(float* p, float v) { *p = v; }
__device__ __forceinline__ void storeQ(__hip_bfloat16* p, float v) { *p = __float2bfloat16(v); }
__device__ __forceinline__ float loadQ(const float* p) { return *p; }
__device__ __forceinline__ float loadQ(const __hip_bfloat16* p) { return __bfloat162float(*p); }

// -------- prep: transpose k_w1 (16x64 -> 64x16) and k_w2 (64x64) -------------
__global__ __launch_bounds__(256) void prep_kernel(
    const float* __restrict__ w1, const float* __restrict__ w2,
    float* __restrict__ w1T, float* __restrict__ w2T) {
    int t = blockIdx.x * 256 + threadIdx.x;
    if (t < NES * HID) {
        int i = t / HID, j = t % HID;
        w1T[j * NES + i] = w1[t];
    }
    if (t < HID * HID) {
        int i = t / HID, j = t % HID;
        w2T[j * HID + i] = w2[t];
    }
}

// -------- mbuild: M[hg][i][j][hl], C0[hg][i][hl], Mb[h][j], c1[h] ------------
__global__ __launch_bounds__(256) void mbuild_kernel(
    const float* __restrict__ qw3, const float* __restrict__ qb3,
    const float* __restrict__ kw3, const float* __restrict__ kb3,
    float* __restrict__ M, float* __restrict__ C0,
    float* __restrict__ Mb, float* __restrict__ c1) {
    const int b = blockIdx.x, t = threadIdx.x;
    if (b < 256) {                     // M: 65536 entries
        const int o  = b * 256 + t;
        const int hl = o & 3, j = (o >> 2) & 63, i = (o >> 8) & 63, hg = o >> 14;
        const int h  = hg * 4 + hl;
        const float* ka = kw3 + (size_t)i * OUTD + h * HEAD_DIM;
        const float* qa = qw3 + (size_t)j * OUTD + h * HEAD_DIM;
        float s = 0.f;
        #pragma unroll
        for (int d = 0; d < HEAD_DIM; ++d) s += ka[d] * qa[d];
        M[o] = s;
    } else if (b < 260) {              // C0: 1024 entries, layout [hg][i][hl]
        const int o  = (b - 256) * 256 + t;
        const int hl = o & 3, i = (o >> 2) & 63, hg = o >> 8;
        const int h  = hg * 4 + hl;
        float s = 0.f;
        #pragma unroll
        for (int d = 0; d < HEAD_DIM; ++d)
            s += kw3[(size_t)i * OUTD + h * HEAD_DIM + d] * qb3[h * HEAD_DIM + d];
        C0[o] = s;
    } else if (b < 264) {              // Mb: [h][j]
        const int o = (b - 260) * 256 + t;
        const int h = o >> 6, j = o & 63;
        float s = 0.f;
        #pragma unroll
        for (int d = 0; d < HEAD_DIM; ++d)
            s += kb3[h * HEAD_DIM + d] * qw3[(size_t)j * OUTD + h * HEAD_DIM + d];
        Mb[o] = s;
    } else {                           // c1: 16
        if (t < HEADS) {
            float s = 0.f;
            #pragma unroll
            for (int d = 0; d < HEAD_DIM; ++d)
                s += kb3[t * HEAD_DIM + d] * qb3[t * HEAD_DIM + d];
            c1[t] = s;
        }
    }
}

// -------- h2q: Q-MLP layers 1-2 per node + Sn = h2.Mb + c1 -------------------
__global__ __launch_bounds__(256) void h2q_kernel(
    const float* __restrict__ node_attrs,
    const float* __restrict__ w1, const float* __restrict__ b1,
    const float* __restrict__ w2, const float* __restrict__ b2,
    const float* __restrict__ Mb, const float* __restrict__ c1,
    float* __restrict__ h2buf, float* __restrict__ Sn) {
    __shared__ float xs[4][NNS];
    __shared__ float h1s[4][HID];
    __shared__ float h2s[4][HID];
    __shared__ float Mbs[HEADS][65];
    __shared__ float c1s[HEADS];
    const int t = threadIdx.x, wid = t >> 6, lane = t & 63;
    for (int o = t; o < HEADS * HID; o += 256) Mbs[o >> 6][o & 63] = Mb[o];
    if (t < HEADS) c1s[t] = c1[t];

    const int n = blockIdx.x * 4 + wid;
    const bool act = n < N_NODES;
    xs[wid][lane] = act ? node_attrs[(size_t)n * NNS + lane] : 0.0f;
    __syncthreads();

    float a = b1[lane];
    #pragma unroll
    for (int i = 0; i < NNS; ++i) a += xs[wid][i] * w1[i * HID + lane];
    h1s[wid][lane] = silu_f(a);
    __syncthreads();

    float a2 = b2[lane];
    #pragma unroll
    for (int i = 0; i < HID; ++i) a2 += h1s[wid][i] * w2[i * HID + lane];
    const float h2v = silu_f(a2);
    h2s[wid][lane] = h2v;
    if (act) h2buf[(size_t)n * HID + lane] = h2v;
    __syncthreads();

    const int h = lane & 15, q = lane >> 4;
    float s = 0.f;
    #pragma unroll
    for (int jj = 0; jj < 16; ++jj) s += h2s[wid][q * 16 + jj] * Mbs[h][q * 16 + jj];
    s += __shfl_xor(s, 16);
    s += __shfl_xor(s, 32);
    if (act && lane < HEADS) Sn[(size_t)n * HEADS + lane] = s + c1s[lane];
}

// -------- papply: P[n][hg][j][hl] = h2.Mreg + C0 (persistent M regs) ---------
__global__ __launch_bounds__(256) void papply_kernel(
    const float* __restrict__ h2buf, const float* __restrict__ M,
    const float* __restrict__ C0, float* __restrict__ Pn) {
    const int t  = threadIdx.x;
    const int hg = blockIdx.y;

    float Mreg[HID];
    const float* msrc = M + (size_t)hg * 16384 + (t >> 2) * 256 + (t & 3);
    #pragma unroll
    for (int j = 0; j < HID; ++j) Mreg[j] = msrc[j * 4];
    const float c0 = C0[hg * 256 + t];

    __shared__ float h2s[4][HID];
    const int n0 = blockIdx.x * NPB_A;
    #pragma unroll 1
    for (int s4 = 0; s4 < NPB_A / 4; ++s4) {
        const int nb = n0 + s4 * 4;
        const int nl = nb + (t >> 6);
        const float v = (nl < N_NODES) ? h2buf[(size_t)nl * HID + (t & 63)] : 0.f;
        __syncthreads();
        h2s[t >> 6][t & 63] = v;
        __syncthreads();
        #pragma unroll 1
        for (int mm = 0; mm < 4; ++mm) {
            const int n = nb + mm;
            if (n >= N_NODES) break;
            float acc0 = c0, acc1 = 0.f;
            #pragma unroll
            for (int j = 0; j < HID; j += 2) {
                acc0 += h2s[mm][j]     * Mreg[j];
                acc1 += h2s[mm][j + 1] * Mreg[j + 1];
            }
            Pn[(size_t)n * 1024 + hg * 256 + t] = acc0 + acc1;
        }
    }
}

// -------- CSR build ----------------------------------------------------------
__global__ __launch_bounds__(256) void zero_counts_kernel(int* __restrict__ counts) {
    int t = blockIdx.x * 256 + threadIdx.x;
    if (t < N_NODES) counts[t] = 0;
}
__global__ __launch_bounds__(256) void hist_kernel(const int* __restrict__ center,
                                                   int* __restrict__ counts) {
    int e = blockIdx.x * 256 + threadIdx.x;
    if (e < N_EDGES) atomicAdd(&counts[center[e]], 1);
}
__global__ __launch_bounds__(SCAN_B) void scan1_kernel(
    const int* __restrict__ counts, int* __restrict__ incl, int* __restrict__ blockSums) {
    __shared__ int sm[SCAN_B];
    const int gid = blockIdx.x * SCAN_B + threadIdx.x;
    sm[threadIdx.x] = (gid < N_NODES) ? counts[gid] : 0;
    __syncthreads();
    #pragma unroll 1
    for (int off = 1; off < SCAN_B; off <<= 1) {
        int t = (threadIdx.x >= off) ? sm[threadIdx.x - off] : 0;
        __syncthreads();
        sm[threadIdx.x] += t;
        __syncthreads();
    }
    if (gid < N_NODES) incl[gid] = sm[threadIdx.x];
    if (threadIdx.x == SCAN_B - 1) blockSums[blockIdx.x] = sm[threadIdx.x];
}
__global__ void scan2_kernel(int* __restrict__ blockSums) {
    if (threadIdx.x == 0 && blockIdx.x == 0) {
        int run = 0;
        for (int i = 0; i < NSB; ++i) { int t = blockSums[i]; blockSums[i] = run; run += t; }
    }
}
__global__ __launch_bounds__(SCAN_B) void scan3_kernel(
    const int* __restrict__ counts, const int* __restrict__ incl,
    const int* __restrict__ blockSums, int* __restrict__ rowStart,
    int* __restrict__ cursor) {
    const int gid = blockIdx.x * SCAN_B + threadIdx.x;
    if (gid < N_NODES) {
        const int excl = incl[gid] - counts[gid] + blockSums[blockIdx.x];
        rowStart[gid] = excl;
        cursor[gid]   = excl;
    }
    if (gid == 0) rowStart[N_NODES] = N_EDGES;
}
__global__ __launch_bounds__(256) void fill_kernel(const int* __restrict__ center,
                                                   int* __restrict__ cursor,
                                                   int* __restrict__ edgeList,
                                                   int* __restrict__ nodeOf) {
    int e = blockIdx.x * 256 + threadIdx.x;
    if (e < N_EDGES) {
        const int c = center[e];
        int pos = atomicAdd(&cursor[c], 1);
        edgeList[pos] = e;
        nodeOf[pos]   = c;
    }
}

// -------- W-pass v5: fused, quad accumulators (round-13 config, frozen) ------
__global__ __launch_bounds__(256, 2) void wpass5_kernel(
    const int* __restrict__ edgeList, const int* __restrict__ nodeOf,
    const float* __restrict__ edge_feat,
    const float* __restrict__ w1T, const float* __restrict__ b1,
    const float* __restrict__ w2T, const float* __restrict__ b2,
    const float* __restrict__ Pn, const float* __restrict__ Sn,
    float* __restrict__ Wbuf) {
    const int p = blockIdx.x * 256 + threadIdx.x;
    if (p >= N_EDGES) return;
    const int e = edgeList[p];
    const int c = nodeOf[p];

    float x[NES];
    const float4* ef4 = reinterpret_cast<const float4*>(edge_feat + (size_t)e * EDGE_DIM);
    #pragma unroll
    for (int i = 0; i < NES / 4; ++i) {
        float4 t = ef4[i];
        x[4*i+0] = t.x; x[4*i+1] = t.y; x[4*i+2] = t.z; x[4*i+3] = t.w;
    }

    float h1[HID];
    #pragma unroll
    for (int j = 0; j < HID; ++j) {
        float a0 = 0.f, a1 = 0.f, a2 = 0.f, a3 = 0.f;
        const float* wr = w1T + j * NES;
        #pragma unroll
        for (int i = 0; i < NES; i += 4) {
            a0 += x[i + 0] * wr[i + 0];
            a1 += x[i + 1] * wr[i + 1];
            a2 += x[i + 2] * wr[i + 2];
            a3 += x[i + 3] * wr[i + 3];
        }
        h1[j] = silu_f(b1[j] + ((a0 + a1) + (a2 + a3)));
    }

    float wacc[HEADS];
    {
        const float4* s4 = (const float4*)(Sn + (size_t)c * HEADS);
        #pragma unroll
        for (int k = 0; k < 4; ++k) {
            float4 v = s4[k];
            wacc[4*k+0] = v.x; wacc[4*k+1] = v.y; wacc[4*k+2] = v.z; wacc[4*k+3] = v.w;
        }
    }

    const float* prow = Pn + (size_t)c * 1024;
    #pragma unroll 2
    for (int j = 0; j < HID; ++j) {
        float a0 = 0.f, a1 = 0.f, a2 = 0.f, a3 = 0.f;
        const float* wr = w2T + j * HID;
        #pragma unroll
        for (int i = 0; i < HID; i += 4) {
            a0 += h1[i + 0] * wr[i + 0];
            a1 += h1[i + 1] * wr[i + 1];
            a2 += h1[i + 2] * wr[i + 2];
            a3 += h1[i + 3] * wr[i + 3];
        }
        const float h2 = silu_f(b2[j] + ((a0 + a1) + (a2 + a3)));
        #pragma unroll
        for (int hg = 0; hg < 4; ++hg) {
            const float4 pv = *(const float4*)(prow + hg * 256 + j * 4);
            wacc[hg*4+0] += h2 * pv.x;
            wacc[hg*4+1] += h2 * pv.y;
            wacc[hg*4+2] += h2 * pv.z;
            wacc[hg*4+3] += h2 * pv.w;
        }
    }

    float4* wrow = (float4*)(Wbuf + (size_t)p * HEADS);
    #pragma unroll
    for (int k = 0; k < 4; ++k) {
        wrow[k] = make_float4(wacc[4*k+0] * ISQRTD, wacc[4*k+1] * ISQRTD,
                              wacc[4*k+2] * ISQRTD, wacc[4*k+3] * ISQRTD);
    }
}

// -------- node gather v5: ONLINE softmax (1 stats pass) + weighted x4 --------
__global__ __launch_bounds__(256) void gather5_kernel(
    const int* __restrict__ rowStart, const int* __restrict__ edgeList,
    const float* __restrict__ edge_feat, const float* __restrict__ Wbuf,
    float* __restrict__ out) {
    const int wid  = threadIdx.x >> 6;
    const int lane = threadIdx.x & 63;
    const int n = blockIdx.x * 4 + wid;
    if (n >= N_NODES) return;
    const int rs = rowStart[n];
    const int d  = rowStart[n + 1] - rs;

    const int c0 = lane, c1 = lane + 64, c2 = lane + 128;
    const int h0 = headOf(c0);
    const int h1 = headOf(c1);
    const int h2 = (c2 < EDGE_DIM) ? headOf(c2) : 0;
    const bool has2 = (c2 < EDGE_DIM);

    float acc0 = 0.f, acc1 = 0.f, acc2 = 0.f;
    if (d > 0) {
        const int hh  = lane & 15;
        const int sub = lane >> 4;

        // single online pass: running (m, s) per sub-lane
        float m = -3.0e38f, s = 0.f;
        for (int i = sub; i < d; i += 4) {
            const float w = Wbuf[(size_t)(rs + i) * HEADS + hh];
            const float mn = fmaxf(m, w);
            s = s * __expf(m - mn) + __expf(w - mn);
            m = mn;
        }
        // merge (m,s) pairs across the 4 sub-lanes
        #pragma unroll
        for (int mask = 16; mask <= 32; mask <<= 1) {
            const float om = __shfl_xor(m, mask);
            const float os = __shfl_xor(s, mask);
            const float mn = fmaxf(m, om);
            s = s * __expf(m - mn) + os * __expf(om - mn);
            m = mn;
        }
        const float rden = 1.0f / s;

        int i = 0;
        for (; i + 4 <= d; i += 4) {
            const int eA = edgeList[rs + i + 0];
            const int eB = edgeList[rs + i + 1];
            const int eC = edgeList[rs + i + 2];
            const int eD = edgeList[rs + i + 3];
            const float wA = Wbuf[(size_t)(rs + i + 0) * HEADS + hh];
            const float wB = Wbuf[(size_t)(rs + i + 1) * HEADS + hh];
            const float wC = Wbuf[(size_t)(rs + i + 2) * HEADS + hh];
            const float wD = Wbuf[(size_t)(rs + i + 3) * HEADS + hh];
            const float* frA = edge_feat + (size_t)eA * EDGE_DIM;
            const float* frB = edge_feat + (size_t)eB * EDGE_DIM;
            const float* frC = edge_feat + (size_t)eC * EDGE_DIM;
            const float* frD = edge_feat + (size_t)eD * EDGE_DIM;
            const float fA0 = frA[c0], fB0 = frB[c0], fC0 = frC[c0], fD0 = frD[c0];
            const float fA1 = frA[c1], fB1 = frB[c1], fC1 = frC[c1], fD1 = frD[c1];
            const float fA2 = has2 ? frA[c2] : 0.f;
            const float fB2 = has2 ? frB[c2] : 0.f;
            const float fC2 = has2 ? frC[c2] : 0.f;
            const float fD2 = has2 ? frD[c2] : 0.f;

            const float aLA = __expf(wA - m) * rden;
            const float aLB = __expf(wB - m) * rden;
            const float aLC = __expf(wC - m) * rden;
            const float aLD = __expf(wD - m) * rden;
            const float aA0 = __shfl(aLA, h0), aB0 = __shfl(aLB, h0);
            const float aC0 = __shfl(aLC, h0), aD0 = __shfl(aLD, h0);
            const float aA1 = __shfl(aLA, h1), aB1 = __shfl(aLB, h1);
            const float aC1 = __shfl(aLC, h1), aD1 = __shfl(aLD, h1);
            const float aA2 = __shfl(aLA, h2), aB2 = __shfl(aLB, h2);
            const float aC2 = __shfl(aLC, h2), aD2 = __shfl(aLD, h2);

            acc0 += (fA0 * aA0 + fB0 * aB0) + (fC0 * aC0 + fD0 * aD0);
            acc1 += (fA1 * aA1 + fB1 * aB1) + (fC1 * aC1 + fD1 * aD1);
            acc2 += (fA2 * aA2 + fB2 * aB2) + (fC2 * aC2 + fD2 * aD2);
        }
        for (; i < d; ++i) {
            const int eA = edgeList[rs + i];
            const float wA = Wbuf[(size_t)(rs + i) * HEADS + hh];
            const float* frA = edge_feat + (size_t)eA * EDGE_DIM;
            const float aLA = __expf(wA - m) * rden;
            const float aA0 = __shfl(aLA, h0);
            const float aA1 = __shfl(aLA, h1);
            const float aA2 = __shfl(aLA, h2);
            acc0 += frA[c0] * aA0;
            acc1 += frA[c1] * aA1;
            if (has2) acc2 += frA[c2] * aA2;
        }
    }
    float* orow = out + (size_t)n * EDGE_DIM;
    orow[c0] = acc0;
    orow[c1] = acc1;
    if (has2) orow[c2] = acc2;
}

// ==================== fallback-only kernels (small workspace) ================
template <typename QT>
__global__ __launch_bounds__(256) void qmlp_kernel(
    const float* __restrict__ node_attrs,
    const float* __restrict__ w1, const float* __restrict__ b1,
    const float* __restrict__ w2, const float* __restrict__ b2,
    const float* __restrict__ w3, const float* __restrict__ b3,
    QT* __restrict__ qn) {
    __shared__ float xs[4][NNS];
    __shared__ float hs[4][HID];
    const int wid  = threadIdx.x >> 6;
    const int lane = threadIdx.x & 63;
    const int node = blockIdx.x * 4 + wid;
    const bool act = node < N_NODES;

    xs[wid][lane] = act ? node_attrs[(size_t)node * NNS + lane] : 0.0f;
    __syncthreads();
    float a = b1[lane];
    #pragma unroll
    for (int i = 0; i < NNS; ++i) a += xs[wid][i] * w1[i * HID + lane];
    a = silu_f(a);
    hs[wid][lane] = a;
    __syncthreads();
    float a2 = b2[lane];
    #pragma unroll
    for (int i = 0; i < HID; ++i) a2 += hs[wid][i] * w2[i * HID + lane];
    a2 = silu_f(a2);
    __syncthreads();
    xs[wid][lane] = a2;
    __syncthreads();
    if (act) {
        #pragma unroll 1
        for (int j8 = 0; j8 < 8; ++j8) {
            const int col = j8 * 64 + lane;
            float acc = b3[col];
            #pragma unroll
            for (int i = 0; i < HID; ++i) acc += xs[wid][i] * w3[i * OUTD + col];
            storeQ(qn + (size_t)node * OUTD + col, acc);
        }
    }
}

__global__ __launch_bounds__(256) void init_kernel(float* __restrict__ out,
                                                   float* __restrict__ denom,
                                                   unsigned* __restrict__ segmax) {
    int t = blockIdx.x * 256 + threadIdx.x;
    if (t < N_NODES * EDGE_DIM) out[t] = 0.0f;
    if (t < N_NODES * HEADS) {
        denom[t]  = 0.0f;
        segmax[t] = 0u;
    }
}

template <typename QT>
__global__ __launch_bounds__(256) void kmlp_kernel(
    const int* __restrict__ center, const float* __restrict__ edge_feat,
    const float* __restrict__ w1, const float* __restrict__ b1,
    const float* __restrict__ w2, const float* __restrict__ b2,
    const float* __restrict__ w3, const float* __restrict__ b3,
    const QT* __restrict__ qn, float* __restrict__ Wbuf,
    unsigned* __restrict__ segmax) {
    const int e = blockIdx.x * 256 + threadIdx.x;
    if (e >= N_EDGES) return;
    const int c = center[e];
    float x[NES];
    const float4* ef4 = reinterpret_cast<const float4*>(edge_feat + (size_t)e * EDGE_DIM);
    #pragma unroll
    for (int i = 0; i < NES / 4; ++i) {
        float4 t = ef4[i];
        x[4*i+0] = t.x; x[4*i+1] = t.y; x[4*i+2] = t.z; x[4*i+3] = t.w;
    }
    float h1[HID];
    #pragma unroll
    for (int j = 0; j < HID; ++j) {
        float a = 0.f;
        #pragma unroll
        for (int i = 0; i < NES; ++i) a += x[i] * w1[i * HID + j];
        h1[j] = silu_f(b1[j] + a);
    }
    float h2[HID];
    #pragma unroll
    for (int j = 0; j < HID; ++j) {
        float a = 0.f;
        #pragma unroll
        for (int i = 0; i < HID; ++i) a += h1[i] * w2[i * HID + j];
        h2[j] = silu_f(b2[j] + a);
    }
    const QT* q = qn + (size_t)c * OUTD;
    #pragma unroll 1
    for (int h = 0; h < HEADS; ++h) {
        float wacc = 0.0f;
        #pragma unroll 1
        for (int jj = 0; jj < HEAD_DIM; ++jj) {
            const int j = h * HEAD_DIM + jj;
            float a = 0.f;
            #pragma unroll
            for (int i = 0; i < HID; ++i) a += h2[i] * w3[i * OUTD + j];
            wacc += (b3[j] + a) * loadQ(q + j);
        }
        const float Wv = wacc * ISQRTD;
        Wbuf[(size_t)e * HEADS + h] = Wv;
        atomicMax(&segmax[c * HEADS + h], fenc(Wv));
    }
}

__global__ __launch_bounds__(256) void ex_denom_kernel(
    const int* __restrict__ center, const unsigned* __restrict__ segmax,
    float* __restrict__ Wbuf, float* __restrict__ denom) {
    const int t = blockIdx.x * 256 + threadIdx.x;
    if (t >= N_EDGES * HEADS) return;
    const int e = t >> 4;
    const int h = t & 15;
    const int c = center[e];
    const float m  = fdec(segmax[c * HEADS + h]);
    const float ex = __expf(Wbuf[t] - m);
    Wbuf[t] = ex;
    atomicAdd(&denom[c * HEADS + h], ex);
}

__global__ __launch_bounds__(256) void attn_kernel(
    const int* __restrict__ center, float* __restrict__ Wbuf,
    const float* __restrict__ denom) {
    const int t = blockIdx.x * 256 + threadIdx.x;
    if (t >= N_EDGES * HEADS) return;
    const int e = t >> 4;
    const int h = t & 15;
    Wbuf[t] = Wbuf[t] / denom[center[e] * HEADS + h];
}

__global__ __launch_bounds__(256) void scatter4_kernel(
    const int* __restrict__ center, const float* __restrict__ edge_feat,
    const float* __restrict__ attn, float* __restrict__ out) {
    const int t = blockIdx.x * 256 + threadIdx.x;
    if (t >= N_EDGES * (EDGE_DIM / 4)) return;
    const int e  = t / (EDGE_DIM / 4);
    const int cg = t - e * (EDGE_DIM / 4);
    const int c  = center[e];
    const float4 f = *(const float4*)(edge_feat + (size_t)e * EDGE_DIM + cg * 4);
    const float* arow = attn + (size_t)e * HEADS;
    const float vals[4] = {f.x, f.y, f.z, f.w};
    #pragma unroll
    for (int k = 0; k < 4; ++k) {
        const int col = cg * 4 + k;
        const int h = headOf(col);
        atomicAdd(out + (size_t)c * EDGE_DIM + col, vals[k] * arow[h]);
    }
}

extern "C" void kernel_launch(void* const* d_in, const int* in_sizes, int n_in,
                              void* d_out, int out_size, void* d_ws, size_t ws_size,
                              hipStream_t stream) {
    const int*   edge_index = (const int*)d_in[0];
    const float* edge_feat  = (const float*)d_in[1];
    const float* node_attrs = (const float*)d_in[2];
    const float* q_w1 = (const float*)d_in[3];
    const float* q_b1 = (const float*)d_in[4];
    const float* q_w2 = (const float*)d_in[5];
    const float* q_b2 = (const float*)d_in[6];
    const float* q_w3 = (const float*)d_in[7];
    const float* q_b3 = (const float*)d_in[8];
    const float* k_w1 = (const float*)d_in[9];
    const float* k_b1 = (const float*)d_in[10];
    const float* k_w2 = (const float*)d_in[11];
    const float* k_b2 = (const float*)d_in[12];
    const float* k_w3 = (const float*)d_in[13];
    const float* k_b3 = (const float*)d_in[14];
    const int* center = edge_index;
    float* out = (float*)d_out;

    const size_t szP   = (size_t)N_NODES * HID * HEADS * sizeof(float);  // 204.8 MB
    const size_t szH2  = (size_t)N_NODES * HID * sizeof(float);          //  12.8 MB
    const size_t szS   = (size_t)N_NODES * HEADS * sizeof(float);        //   3.2 MB
    const size_t szW   = (size_t)N_EDGES * HEADS * sizeof(float);        //  25.6 MB
    const size_t szM   = (size_t)HID * HID * HEADS * sizeof(float);      // 256 KB
    const size_t szMisc= (1024 + 1024 + 64 + NES * HID + HID * HID) * sizeof(float);
    const size_t szCSR = ((size_t)4 * N_NODES + N_NODES + 1 + 256 + 2 * N_EDGES) * sizeof(int);

    const int h2qGrid     = (N_NODES + 3) / 4;              // 12500
    const dim3 papGrid((N_NODES + NPB_A - 1) / NPB_A, 4);   // (782, 4)
    const int edgeGrid    = (N_EDGES + 255) / 256;
    const int nodeGrid256 = (N_NODES + 255) / 256;
    const int gatherGrid  = (N_NODES + 3) / 4;
    const int ehGrid      = (N_EDGES * HEADS + 255) / 256;

    const size_t need = szP + szH2 + szS + szW + szM + szMisc + szCSR + 4096;

    if (ws_size >= need) {
        char* p = (char*)d_ws;
        float* Pn    = (float*)p;  p += szP;
        float* h2buf = (float*)p;  p += szH2;
        float* Sn    = (float*)p;  p += szS;
        float* Wbuf  = (float*)p;  p += szW;
        float* Mmat  = (float*)p;  p += szM;
        float* C0    = (float*)p;  p += 1024 * sizeof(float);
        float* Mb    = (float*)p;  p += 1024 * sizeof(float);
        float* c1v   = (float*)p;  p += 64 * sizeof(float);
        float* w1T   = (float*)p;  p += NES * HID * sizeof(float);
        float* w2T   = (float*)p;  p += HID * HID * sizeof(float);
        int* counts   = (int*)p;
        int* incl     = counts + N_NODES;
        int* rowStart = incl + N_NODES;          // N_NODES+1
        int* cursor   = rowStart + N_NODES + 1;
        int* blockSums= cursor + N_NODES;
        int* edgeList = blockSums + 256;
        int* nodeOf   = edgeList + N_EDGES;

        prep_kernel<<<16, 256, 0, stream>>>(k_w1, k_w2, w1T, w2T);
        mbuild_kernel<<<265, 256, 0, stream>>>(q_w3, q_b3, k_w3, k_b3, Mmat, C0, Mb, c1v);
        h2q_kernel<<<h2qGrid, 256, 0, stream>>>(
            node_attrs, q_w1, q_b1, q_w2, q_b2, Mb, c1v, h2buf, Sn);
        papply_kernel<<<papGrid, 256, 0, stream>>>(h2buf, Mmat, C0, Pn);

        zero_counts_kernel<<<nodeGrid256, 256, 0, stream>>>(counts);
        hist_kernel<<<edgeGrid, 256, 0, stream>>>(center, counts);
        scan1_kernel<<<NSB, SCAN_B, 0, stream>>>(counts, incl, blockSums);
        scan2_kernel<<<1, 64, 0, stream>>>(blockSums);
        scan3_kernel<<<NSB, SCAN_B, 0, stream>>>(counts, incl, blockSums, rowStart, cursor);
        fill_kernel<<<edgeGrid, 256, 0, stream>>>(center, cursor, edgeList, nodeOf);

        wpass5_kernel<<<edgeGrid, 256, 0, stream>>>(
            edgeList, nodeOf, edge_feat, w1T, k_b1, w2T, k_b2, Pn, Sn, Wbuf);
        gather5_kernel<<<gatherGrid, 256, 0, stream>>>(rowStart, edgeList, edge_feat, Wbuf, out);
        return;
    }

    // ---------------- fallback: atomic pipeline (small ws) -------------------
    const size_t szQ   = (size_t)N_NODES * OUTD * sizeof(float);
    char* p = (char*)d_ws;
    float*    Wbuf   = (float*)p;    p += szW;
    float*    denom  = (float*)p;    p += szS;
    unsigned* segmax = (unsigned*)p; p += szS;
    const size_t fbase = (size_t)(p - (char*)d_ws);
    const bool qf32 = ws_size >= fbase + szQ;

    const int initGrid    = (N_NODES * EDGE_DIM + 255) / 256;
    const int scatterGrid = (N_EDGES * (EDGE_DIM / 4) + 255) / 256;
    const int qmlpGrid    = (N_NODES + 3) / 4;

    init_kernel<<<initGrid, 256, 0, stream>>>(out, denom, segmax);
    if (qf32) {
        float* qn = (float*)p;
        qmlp_kernel<float><<<qmlpGrid, 256, 0, stream>>>(
            node_attrs, q_w1, q_b1, q_w2, q_b2, q_w3, q_b3, qn);
        kmlp_kernel<float><<<edgeGrid, 256, 0, stream>>>(
            center, edge_feat, k_w1, k_b1, k_w2, k_b2, k_w3, k_b3, qn, Wbuf, segmax);
    } else {
        __hip_bfloat16* qn = (__hip_bfloat16*)p;
        qmlp_kernel<__hip_bfloat16><<<qmlpGrid, 256, 0, stream>>>(
            node_attrs, q_w1, q_b1, q_w2, q_b2, q_w3, q_b3, qn);
        kmlp_kernel<__hip_bfloat16><<<edgeGrid, 256, 0, stream>>>(
            center, edge_feat, k_w1, k_b1, k_w2, k_b2, k_w3, k_b3, qn, Wbuf, segmax);
    }
    ex_denom_kernel<<<ehGrid, 256, 0, stream>>>(center, segmax, Wbuf, denom);
    attn_kernel<<<ehGrid, 256, 0, stream>>>(center, Wbuf, denom);
    scatter4_kernel<<<scatterGrid, 256, 0, stream>>>(center, edge_feat, Wbuf, out);
}